// Round 1
// baseline (6398.288 us; speedup 1.0000x reference)
//
#include <hip/hip_runtime.h>
#include <hip/hip_bf16.h>
#include <cstdint>

typedef short short8 __attribute__((ext_vector_type(8)));
typedef float f32x4 __attribute__((ext_vector_type(4)));
typedef unsigned short u16;

#define DEVINL __device__ __forceinline__

DEVINL u16 f32_to_bf16(float f) {
  uint32_t u = __builtin_bit_cast(uint32_t, f);
  u += 0x7FFFu + ((u >> 16) & 1u);   // RTNE; inputs are finite
  return (u16)(u >> 16);
}
DEVINL float bf16_to_f32(u16 b) {
  return __builtin_bit_cast(float, ((uint32_t)b) << 16);
}
DEVINL f32x4 mfma16(short8 a, short8 b, f32x4 c) {
  return __builtin_amdgcn_mfma_f32_16x16x32_bf16(a, b, c, 0, 0, 0);
}
DEVINL float tanh_fast(float x) {
  float xc = fminf(fmaxf(x, -9.f), 9.f);
  float e  = __expf(2.f * xc);
  return __fdividef(e - 1.f, e + 1.f);
}

// ---------------- fp32 -> bf16 convert ----------------
__global__ void conv_bf16(const float* __restrict__ src, u16* __restrict__ dst, long n) {
  long i = ((long)blockIdx.x * blockDim.x + threadIdx.x) * 4;
  long stride = (long)gridDim.x * blockDim.x * 4;
  for (; i < n; i += stride) {
    float4 v = *(const float4*)(src + i);
    uint64_t p = (uint64_t)f32_to_bf16(v.x)
               | ((uint64_t)f32_to_bf16(v.y) << 16)
               | ((uint64_t)f32_to_bf16(v.z) << 32)
               | ((uint64_t)f32_to_bf16(v.w) << 48);
    *(uint64_t*)(dst + i) = p;
  }
}

__global__ void prep_bias(const float* __restrict__ bih, const float* __restrict__ bhh,
                          float* __restrict__ b1, float* __restrict__ b2) {
  int i = threadIdx.x;   // 512 threads
  b1[i] = bih[i]       + bhh[i];
  b2[i] = bih[512 + i] + bhh[512 + i];
}

// ---------------- GEMM: C[M,N] = A[M,K] @ B[N,K]^T + bias ----------------
// A,B bf16 row-major (K contiguous). 128x128 tile, BK=64, 8 waves.
template <bool OUT_BF16>
__launch_bounds__(512, 2)
__global__ void gemm_bt(const u16* __restrict__ A, const u16* __restrict__ B,
                        const float* __restrict__ bias, void* __restrict__ out,
                        int M, int N, int K) {
  __shared__ u16 lA[128 * 64];
  __shared__ u16 lB[128 * 64];
  const int tid  = threadIdx.x;
  const int lane = tid & 63;
  const int wave = tid >> 6;          // 0..7
  const int wr = wave >> 2;           // 0..1  (M dir, 64 rows)
  const int wc = wave & 3;            // 0..3  (N dir, 32 cols)
  const int q   = lane >> 4;          // 0..3
  const int r16 = lane & 15;
  const int brow = blockIdx.x * 128;
  const int bcol = blockIdx.y * 128;

  f32x4 acc[4][2];
#pragma unroll
  for (int i = 0; i < 4; ++i)
#pragma unroll
    for (int j = 0; j < 2; ++j) acc[i][j] = (f32x4){0.f, 0.f, 0.f, 0.f};

  const int nkt = K >> 6;   // K/64
  for (int kt = 0; kt < nkt; ++kt) {
    // stage A,B tiles: 1024 chunks of 16B each, 2 per thread, XOR-swizzled dest
#pragma unroll
    for (int s = 0; s < 2; ++s) {
      int c   = tid * 2 + s;
      int row = c >> 3;             // 0..127
      int cb  = (c & 7) * 16;       // byte in 128B row
      int dsw = cb ^ ((row & 7) << 4);
      short8 va = *(const short8*)(A + (size_t)(brow + row) * K + kt * 64 + (cb >> 1));
      *(short8*)((char*)lA + row * 128 + dsw) = va;
      short8 vb = *(const short8*)(B + (size_t)(bcol + row) * K + kt * 64 + (cb >> 1));
      *(short8*)((char*)lB + row * 128 + dsw) = vb;
    }
    __syncthreads();
#pragma unroll
    for (int kk = 0; kk < 2; ++kk) {
      short8 af[4], bfr[2];
#pragma unroll
      for (int mt = 0; mt < 4; ++mt) {
        int row = wr * 64 + mt * 16 + r16;
        int byt = (kk * 64 + q * 16) ^ ((row & 7) << 4);
        af[mt] = *(const short8*)((const char*)lA + row * 128 + byt);
      }
#pragma unroll
      for (int nt = 0; nt < 2; ++nt) {
        int row = wc * 32 + nt * 16 + r16;
        int byt = (kk * 64 + q * 16) ^ ((row & 7) << 4);
        bfr[nt] = *(const short8*)((const char*)lB + row * 128 + byt);
      }
#pragma unroll
      for (int mt = 0; mt < 4; ++mt)
#pragma unroll
        for (int nt = 0; nt < 2; ++nt)
          acc[mt][nt] = mfma16(af[mt], bfr[nt], acc[mt][nt]);
    }
    __syncthreads();
  }

  // epilogue: D row = q*4+reg, col = r16
#pragma unroll
  for (int mt = 0; mt < 4; ++mt) {
#pragma unroll
    for (int nt = 0; nt < 2; ++nt) {
      int jc = bcol + wc * 32 + nt * 16 + r16;
      float bv = bias[jc];
#pragma unroll
      for (int rg = 0; rg < 4; ++rg) {
        int mg = brow + wr * 64 + mt * 16 + q * 4 + rg;
        float v = acc[mt][nt][rg] + bv;
        if (OUT_BF16) ((u16*)out)[(size_t)mg * N + jc] = f32_to_bf16(v);
        else          ((float*)out)[(size_t)mg * N + jc] = v;
      }
    }
  }
}

// ---------------- Recurrence: h_t = tanh(U_t + h_{t-1} @ Whh^T) ----------------
// 8 blocks (one per 16-row batch group), 8 waves each. Whh: 384 cols in VGPRs
// (48/wave), 128 cols in LDS. h double-buffered in LDS (XOR-swizzled rows).
__launch_bounds__(512, 2)
__global__ void rnn_rec(const u16* __restrict__ Whh,   // [512][512] bf16
                        const u16* __restrict__ U,     // [B*T][512] bf16 (pre-act + biases)
                        u16* __restrict__ Hout,        // [B*T][512] bf16
                        float* __restrict__ hidden) {  // [125*512] fp32 (this layer)
  __shared__ u16 wlds[128 * 512];     // 128 KiB: 8 tiles x [16 j][512 k], swizzled
  __shared__ u16 hb[2 * 16 * 512];    // 32 KiB double buffer
  const int tid  = threadIdx.x;
  const int lane = tid & 63;
  const int w    = tid >> 6;          // wave 0..7 -> cols [w*64, w*64+64)
  const int q    = lane >> 4;
  const int r16  = lane & 15;
  const int g    = blockIdx.x;        // batch group, rows g*16..g*16+15
  const int T    = 512;

  // register-resident W: cols w*64 + tt*16 + r16, tt=0..2
  short8 wreg[3][16];
#pragma unroll
  for (int tt = 0; tt < 3; ++tt)
#pragma unroll
    for (int kk = 0; kk < 16; ++kk) {
      int j = w * 64 + tt * 16 + r16;
      wreg[tt][kk] = *(const short8*)(Whh + (size_t)j * 512 + kk * 32 + q * 8);
    }

  // LDS-resident W: cols w*64+48 .. +63 (tile w), swizzled rows
#pragma unroll
  for (int c = 0; c < 16; ++c) {
    int linear = lane * 256 + c * 16;      // byte within 16KB tile
    int jloc = linear >> 10;               // 0..15
    int kb   = linear & 1023;
    short8 v = *(const short8*)(Whh + (size_t)(w * 64 + 48 + jloc) * 512 + (kb >> 1));
    *(short8*)((char*)wlds + w * 16384 + jloc * 1024 + (kb ^ ((jloc & 7) << 4))) = v;
  }

  // zero h buffer 0 (512 thr x 32B = 16 KiB)
  {
    short8 z = {0, 0, 0, 0, 0, 0, 0, 0};
    *(short8*)((char*)hb + tid * 32)      = z;
    *(short8*)((char*)hb + tid * 32 + 16) = z;
  }
  __syncthreads();

  // prefetch U for t=0
  u16 upf[16];
#pragma unroll
  for (int tile = 0; tile < 4; ++tile)
#pragma unroll
    for (int rg = 0; rg < 4; ++rg) {
      int b = g * 16 + q * 4 + rg;
      int j = w * 64 + tile * 16 + r16;
      upf[tile * 4 + rg] = (b < 125) ? U[(size_t)b * T * 512 + j] : (u16)0;
    }

  for (int t = 0; t < T; ++t) {
    const int cur = t & 1, nxt = cur ^ 1;
    f32x4 D[4];
#pragma unroll
    for (int tile = 0; tile < 4; ++tile)
#pragma unroll
      for (int rg = 0; rg < 4; ++rg)
        D[tile][rg] = bf16_to_f32(upf[tile * 4 + rg]);

    // prefetch next step's U (latency hidden under MFMAs)
    {
      int tn = (t + 1 < T) ? (t + 1) : t;
#pragma unroll
      for (int tile = 0; tile < 4; ++tile)
#pragma unroll
        for (int rg = 0; rg < 4; ++rg) {
          int b = g * 16 + q * 4 + rg;
          int j = w * 64 + tile * 16 + r16;
          upf[tile * 4 + rg] = (b < 125) ? U[((size_t)b * T + tn) * 512 + j] : (u16)0;
        }
    }

#pragma unroll
    for (int kk = 0; kk < 16; ++kk) {
      int byt = (kk * 64 + q * 16) ^ ((r16 & 7) << 4);
      short8 a  = *(const short8*)((const char*)hb + cur * 16384 + r16 * 1024 + byt);
      short8 bl = *(const short8*)((const char*)wlds + w * 16384 + r16 * 1024 + byt);
      D[0] = mfma16(a, wreg[0][kk], D[0]);
      D[1] = mfma16(a, wreg[1][kk], D[1]);
      D[2] = mfma16(a, wreg[2][kk], D[2]);
      D[3] = mfma16(a, bl, D[3]);
    }

    // epilogue: tanh, store to LDS (nxt), global H, hidden at t=T-1
#pragma unroll
    for (int tile = 0; tile < 4; ++tile) {
      int j = w * 64 + tile * 16 + r16;
#pragma unroll
      for (int rg = 0; rg < 4; ++rg) {
        int m = q * 4 + rg;
        int b = g * 16 + m;
        float th = tanh_fast(D[tile][rg]);
        u16 hbits = f32_to_bf16(th);
        *(u16*)((char*)hb + nxt * 16384 + m * 1024 + ((j * 2) ^ ((m & 7) << 4))) = hbits;
        if (b < 125) {
          Hout[((size_t)b * T + t) * 512 + j] = hbits;
          if (t == T - 1) hidden[(size_t)b * 512 + j] = th;
        }
      }
    }
    __syncthreads();
  }
}

extern "C" void kernel_launch(void* const* d_in, const int* in_sizes, int n_in,
                              void* d_out, int out_size, void* d_ws, size_t ws_size,
                              hipStream_t stream) {
  const float* x   = (const float*)d_in[0];
  const float* wih = (const float*)d_in[1];   // [2,512,512]
  const float* whh = (const float*)d_in[2];   // [2,512,512]
  const float* bih = (const float*)d_in[3];   // [2,512]
  const float* bhh = (const float*)d_in[4];   // [2,512]
  const float* fcw = (const float*)d_in[5];   // [1024,512]
  const float* fcb = (const float*)d_in[6];   // [1024]

  // workspace layout (all 16B-aligned offsets)
  char* ws = (char*)d_ws;
  u16* Xb   = (u16*)ws;                          // 65,536,000 B
  u16* Hb   = (u16*)(ws + 65536000);             // 65,536,000 B
  u16* Wih1 = (u16*)(ws + 131072000);            // 512 KB each
  u16* Whh1 = Wih1 + 262144;
  u16* Wih2 = Whh1 + 262144;
  u16* Whh2 = Wih2 + 262144;
  u16* FCW  = Whh2 + 262144;                     // 1 MB
  float* b1 = (float*)(FCW + 524288);
  float* b2 = b1 + 512;

  // U scratch lives in d_out (dead before the final FC overwrites it)
  u16*   Ub   = (u16*)d_out;
  float* outp = (float*)d_out;
  float* hid  = outp + 65536000;                 // [2][125][512]

  // converts
  conv_bf16<<<2048, 256, 0, stream>>>(x, Xb, 32768000L);
  conv_bf16<<<256, 256, 0, stream>>>(wih,          Wih1, 262144L);
  conv_bf16<<<256, 256, 0, stream>>>(wih + 262144, Wih2, 262144L);
  conv_bf16<<<256, 256, 0, stream>>>(whh,          Whh1, 262144L);
  conv_bf16<<<256, 256, 0, stream>>>(whh + 262144, Whh2, 262144L);
  conv_bf16<<<512, 256, 0, stream>>>(fcw, FCW, 524288L);
  prep_bias<<<1, 512, 0, stream>>>(bih, bhh, b1, b2);

  dim3 blk(512);
  dim3 g1(500, 4);   // 64000/128 x 512/128
  dim3 g2(500, 8);   // 64000/128 x 1024/128

  // layer 1
  gemm_bt<true><<<g1, blk, 0, stream>>>(Xb, Wih1, b1, Ub, 64000, 512, 512);
  rnn_rec<<<8, blk, 0, stream>>>(Whh1, Ub, Hb, hid);
  // layer 2
  gemm_bt<true><<<g1, blk, 0, stream>>>(Hb, Wih2, b2, Ub, 64000, 512, 512);
  rnn_rec<<<8, blk, 0, stream>>>(Whh2, Ub, Hb, hid + 64000);
  // FC head
  gemm_bt<false><<<g2, blk, 0, stream>>>(Hb, FCW, fcb, d_out, 64000, 1024, 512);

  (void)in_sizes; (void)n_in; (void)out_size; (void)ws_size;
}

// Round 2
// 3786.042 us; speedup vs baseline: 1.6900x; 1.6900x over previous
//
#include <hip/hip_runtime.h>
#include <hip/hip_bf16.h>
#include <cstdint>

typedef short short8 __attribute__((ext_vector_type(8)));
typedef float f32x4 __attribute__((ext_vector_type(4)));
typedef uint32_t u32x2 __attribute__((ext_vector_type(2)));
typedef unsigned short u16;

#define DEVINL __device__ __forceinline__

DEVINL u16 f32_to_bf16(float f) {
  uint32_t u = __builtin_bit_cast(uint32_t, f);
  u += 0x7FFFu + ((u >> 16) & 1u);   // RTNE; inputs are finite
  return (u16)(u >> 16);
}
DEVINL float bf16_to_f32(u16 b) {
  return __builtin_bit_cast(float, ((uint32_t)b) << 16);
}
DEVINL f32x4 mfma16(short8 a, short8 b, f32x4 c) {
  return __builtin_amdgcn_mfma_f32_16x16x32_bf16(a, b, c, 0, 0, 0);
}
DEVINL float tanh_fast(float x) {
  float xc = fminf(fmaxf(x, -9.f), 9.f);
  float e  = __expf(2.f * xc);
  return __fdividef(e - 1.f, e + 1.f);
}

// ---------------- fp32 -> bf16 convert ----------------
__global__ void conv_bf16(const float* __restrict__ src, u16* __restrict__ dst, long n) {
  long i = ((long)blockIdx.x * blockDim.x + threadIdx.x) * 4;
  long stride = (long)gridDim.x * blockDim.x * 4;
  for (; i < n; i += stride) {
    float4 v = *(const float4*)(src + i);
    uint64_t p = (uint64_t)f32_to_bf16(v.x)
               | ((uint64_t)f32_to_bf16(v.y) << 16)
               | ((uint64_t)f32_to_bf16(v.z) << 32)
               | ((uint64_t)f32_to_bf16(v.w) << 48);
    *(uint64_t*)(dst + i) = p;
  }
}

__global__ void prep_bias(const float* __restrict__ bih, const float* __restrict__ bhh,
                          float* __restrict__ b1, float* __restrict__ b2) {
  int i = threadIdx.x;   // 512 threads
  b1[i] = bih[i]       + bhh[i];
  b2[i] = bih[512 + i] + bhh[512 + i];
}

// ---------------- GEMM: C[M,N] = A[M,K] @ B[N,K]^T + bias ----------------
// A,B bf16 row-major (K contiguous). 128x128 tile, BK=64, 8 waves.
// MODE 0: float out, standard [M][N] layout (FC head).
// MODE 1: bf16 out scattered into the rec kernel's U fragment layout:
//   element (b,t,j) -> U'[ ((t*8 + (b>>4))*512 + (j>>6)*64 + ((j>>2)&3)*16 + (b&15))*16
//                          + ((j>>4)&3)*4 + (j&3) ]
template <int MODE>
__launch_bounds__(512, 2)
__global__ void gemm_bt(const u16* __restrict__ A, const u16* __restrict__ B,
                        const float* __restrict__ bias, void* __restrict__ out,
                        int M, int N, int K) {
  __shared__ u16 lA[128 * 64];
  __shared__ u16 lB[128 * 64];
  const int tid  = threadIdx.x;
  const int lane = tid & 63;
  const int wave = tid >> 6;          // 0..7
  const int wr = wave >> 2;           // 0..1  (M dir, 64 rows)
  const int wc = wave & 3;            // 0..3  (N dir, 32 cols)
  const int q   = lane >> 4;          // 0..3
  const int r16 = lane & 15;
  const int brow = blockIdx.x * 128;
  const int bcol = blockIdx.y * 128;

  f32x4 acc[4][2];
#pragma unroll
  for (int i = 0; i < 4; ++i)
#pragma unroll
    for (int j = 0; j < 2; ++j) acc[i][j] = (f32x4){0.f, 0.f, 0.f, 0.f};

  const int nkt = K >> 6;   // K/64
  for (int kt = 0; kt < nkt; ++kt) {
#pragma unroll
    for (int s = 0; s < 2; ++s) {
      int c   = tid * 2 + s;
      int row = c >> 3;             // 0..127
      int cb  = (c & 7) * 16;       // byte in 128B row
      int dsw = cb ^ ((row & 7) << 4);
      short8 va = *(const short8*)(A + (size_t)(brow + row) * K + kt * 64 + (cb >> 1));
      *(short8*)((char*)lA + row * 128 + dsw) = va;
      short8 vb = *(const short8*)(B + (size_t)(bcol + row) * K + kt * 64 + (cb >> 1));
      *(short8*)((char*)lB + row * 128 + dsw) = vb;
    }
    __syncthreads();
#pragma unroll
    for (int kk = 0; kk < 2; ++kk) {
      short8 af[4], bfr[2];
#pragma unroll
      for (int mt = 0; mt < 4; ++mt) {
        int row = wr * 64 + mt * 16 + r16;
        int byt = (kk * 64 + q * 16) ^ ((row & 7) << 4);
        af[mt] = *(const short8*)((const char*)lA + row * 128 + byt);
      }
#pragma unroll
      for (int nt = 0; nt < 2; ++nt) {
        int row = wc * 32 + nt * 16 + r16;
        int byt = (kk * 64 + q * 16) ^ ((row & 7) << 4);
        bfr[nt] = *(const short8*)((const char*)lB + row * 128 + byt);
      }
#pragma unroll
      for (int mt = 0; mt < 4; ++mt)
#pragma unroll
        for (int nt = 0; nt < 2; ++nt)
          acc[mt][nt] = mfma16(af[mt], bfr[nt], acc[mt][nt]);
    }
    __syncthreads();
  }

  // epilogue: D row = q*4+reg (M dir), col = r16 (N dir)
#pragma unroll
  for (int mt = 0; mt < 4; ++mt) {
#pragma unroll
    for (int nt = 0; nt < 2; ++nt) {
      int jc = bcol + wc * 32 + nt * 16 + r16;
      float bv = bias[jc];
      if (MODE == 0) {
#pragma unroll
        for (int rg = 0; rg < 4; ++rg) {
          int mg = brow + wr * 64 + mt * 16 + q * 4 + rg;
          ((float*)out)[(size_t)mg * N + jc] = acc[mt][nt][rg] + bv;
        }
      } else {
        int w2    = jc >> 6;
        int tile2 = (jc >> 4) & 3;
        int q2    = (jc >> 2) & 3;
        int rg2   = jc & 3;
        size_t colpart = (size_t)(w2 * 64 + q2 * 16) * 16 + tile2 * 4 + rg2;
#pragma unroll
        for (int rg = 0; rg < 4; ++rg) {
          int mg = brow + wr * 64 + mt * 16 + q * 4 + rg;
          int bb = mg >> 9;        // batch index (T=512)
          int t2 = mg & 511;       // time index
          size_t idx = (((size_t)t2 * 8 + (bb >> 4)) * 512 + (bb & 15)) * 16 + colpart;
          ((u16*)out)[idx] = f32_to_bf16(acc[mt][nt][rg] + bv);
        }
      }
    }
  }
}

// ---------------- Recurrence: h_t = tanh(U_t + h_{t-1} @ Whh^T) ----------------
// 8 blocks (one per 16-row batch group), 8 waves. Role-swapped MFMA:
// A-operand = W rows (j), B-operand = h rows (m=batch). D[j-local][m].
// W: 48 cols/wave in VGPRs (192) + 16 cols/wave in LDS (128 KiB).
// h double-buffered in LDS (32 KiB), XOR-swizzled. U read in fragment order.
__launch_bounds__(512, 2)
__global__ void rnn_rec(const u16* __restrict__ Whh,
                        const u16* __restrict__ Ufrag,
                        u16* __restrict__ Hout,
                        u16* __restrict__ Hdump,
                        float* __restrict__ hidden) {
  __shared__ u16 wlds[8 * 16 * 512];  // 128 KiB
  __shared__ u16 hb[2 * 16 * 512];    // 32 KiB
  const int tid  = threadIdx.x;
  const int lane = tid & 63;
  const int w    = tid >> 6;          // wave 0..7 -> cols [w*64, w*64+64)
  const int q    = lane >> 4;
  const int r16  = lane & 15;
  const int g    = blockIdx.x;        // batch group
  const int b    = g * 16 + r16;      // this lane's batch row (as MFMA D col)
  const int T    = 512;

  // register W: cols j = w*64 + tt*16 + r16, tt=0..2 ; frag k-chunk = kk*32+q*8
  short8 wreg[3][16];
#pragma unroll
  for (int tt = 0; tt < 3; ++tt)
#pragma unroll
    for (int kk = 0; kk < 16; ++kk)
      wreg[tt][kk] = *(const short8*)(Whh + (size_t)(w * 64 + tt * 16 + r16) * 512 + kk * 32 + q * 8);

  // LDS W: cols w*64+48 .. +63 (tile 3 of this wave), XOR-swizzled rows
#pragma unroll
  for (int c = 0; c < 16; ++c) {
    int linear = lane * 256 + c * 16;
    int jloc = linear >> 10;
    int kb   = linear & 1023;
    short8 v = *(const short8*)(Whh + (size_t)(w * 64 + 48 + jloc) * 512 + (kb >> 1));
    *(short8*)((char*)wlds + w * 16384 + jloc * 1024 + (kb ^ ((jloc & 7) << 4))) = v;
  }

  // zero both h buffers
  {
    short8 z = {0, 0, 0, 0, 0, 0, 0, 0};
#pragma unroll
    for (int i = 0; i < 4; ++i)
      *(short8*)((char*)hb + tid * 64 + i * 16) = z;
  }
  __syncthreads();

  // streaming pointers (1 bump each per step)
  const u16* uptr = Ufrag + ((size_t)g * 512 + tid) * 16;  // step stride: 8*512*16 u16
  u16* hptr;
  int  hstep;
  if (b < 125) {
    hptr  = Hout + (size_t)b * T * 512 + w * 64 + q * 4;
    hstep = 512;
  } else {
    hptr  = Hdump + tid * 64;   // dead rows -> dump zone, no per-step branch
    hstep = 0;
  }

  short8 u0 = *(const short8*)(uptr);
  short8 u1 = *(const short8*)(uptr + 8);

  for (int t = 0; t < T; ++t) {
    const int cur = t & 1;
    const int nxt = cur ^ 1;

    // D init from U fragment (slot = tile*4+rg)
    f32x4 D[4];
#pragma unroll
    for (int tile = 0; tile < 4; ++tile)
#pragma unroll
      for (int rg = 0; rg < 4; ++rg) {
        int s = tile * 4 + rg;
        u16 raw = (u16)(s < 8 ? u0[s] : u1[s - 8]);
        D[tile][rg] = bf16_to_f32(raw);
      }

    // prefetch next step's U (2 x dwordx4, completes under MFMA loop)
    if (t + 1 < T) uptr += 8 * 512 * 16;
    short8 n0 = *(const short8*)(uptr);
    short8 n1 = *(const short8*)(uptr + 8);

#pragma unroll
    for (int kk = 0; kk < 16; ++kk) {
      int byt = (kk * 64 + q * 16) ^ ((r16 & 7) << 4);
      short8 hf = *(const short8*)((const char*)hb + cur * 16384 + r16 * 1024 + byt);
      short8 wl = *(const short8*)((const char*)wlds + w * 16384 + r16 * 1024 + byt);
      D[0] = mfma16(wreg[0][kk], hf, D[0]);
      D[1] = mfma16(wreg[1][kk], hf, D[1]);
      D[2] = mfma16(wreg[2][kk], hf, D[2]);
      D[3] = mfma16(wl, hf, D[3]);
    }

    // epilogue: tanh -> pack 4 consecutive j as b64 -> LDS(nxt) + global H
#pragma unroll
    for (int tile = 0; tile < 4; ++tile) {
      float t0 = tanh_fast(D[tile][0]);
      float t1 = tanh_fast(D[tile][1]);
      float t2 = tanh_fast(D[tile][2]);
      float t3 = tanh_fast(D[tile][3]);
      uint32_t lo = (uint32_t)f32_to_bf16(t0) | ((uint32_t)f32_to_bf16(t1) << 16);
      uint32_t hi = (uint32_t)f32_to_bf16(t2) | ((uint32_t)f32_to_bf16(t3) << 16);
      u32x2 pk; pk[0] = lo; pk[1] = hi;
      int wb = (w * 128 + tile * 32 + q * 8) ^ ((r16 & 7) << 4);
      *(u32x2*)((char*)hb + nxt * 16384 + r16 * 1024 + wb) = pk;
      *(u32x2*)(hptr + tile * 16) = pk;
    }
    hptr += hstep;
    u0 = n0; u1 = n1;
    __syncthreads();
  }

  // final hidden state: h_{T-1} sits in hb buffer 0; linear un-swizzled read
  {
    int m  = tid >> 5;           // 0..15
    int ub = (tid & 31) * 2;     // 16B-unit index within the 1KB row
    if (g * 16 + m < 125) {
#pragma unroll
      for (int p = 0; p < 2; ++p) {
        int unit = ub + p;
        int addr = m * 1024 + ((unit * 16) ^ ((m & 7) << 4));
        short8 hv = *(const short8*)((const char*)hb + addr);
        float* dst = hidden + (size_t)(g * 16 + m) * 512 + unit * 8;
#pragma unroll
        for (int e = 0; e < 8; ++e) dst[e] = bf16_to_f32((u16)hv[e]);
      }
    }
  }
}

extern "C" void kernel_launch(void* const* d_in, const int* in_sizes, int n_in,
                              void* d_out, int out_size, void* d_ws, size_t ws_size,
                              hipStream_t stream) {
  const float* x   = (const float*)d_in[0];
  const float* wih = (const float*)d_in[1];   // [2,512,512]
  const float* whh = (const float*)d_in[2];   // [2,512,512]
  const float* bih = (const float*)d_in[3];   // [2,512]
  const float* bhh = (const float*)d_in[4];   // [2,512]
  const float* fcw = (const float*)d_in[5];   // [1024,512]
  const float* fcb = (const float*)d_in[6];   // [1024]

  // workspace layout
  char* ws = (char*)d_ws;
  u16* Xb    = (u16*)ws;                          // 65,536,000 B
  u16* Hb    = (u16*)(ws + 65536000);             // 65,536,000 B
  u16* Wih1  = (u16*)(ws + 131072000);            // 512 KB each
  u16* Whh1  = Wih1 + 262144;
  u16* Wih2  = Whh1 + 262144;
  u16* Whh2  = Wih2 + 262144;
  u16* FCW   = Whh2 + 262144;                     // 1 MB
  float* b1  = (float*)(FCW + 524288);
  float* b2  = b1 + 512;
  u16* Hdump = (u16*)(ws + 134221824);            // 64 KB dump for dead batch rows

  // U scratch (fragment layout) lives in d_out; dead before FC overwrites it
  u16*   Ub   = (u16*)d_out;
  float* outp = (float*)d_out;
  float* hid  = outp + 65536000;                  // [2][125][512]

  conv_bf16<<<2048, 256, 0, stream>>>(x, Xb, 32768000L);
  conv_bf16<<<256, 256, 0, stream>>>(wih,          Wih1, 262144L);
  conv_bf16<<<256, 256, 0, stream>>>(wih + 262144, Wih2, 262144L);
  conv_bf16<<<256, 256, 0, stream>>>(whh,          Whh1, 262144L);
  conv_bf16<<<256, 256, 0, stream>>>(whh + 262144, Whh2, 262144L);
  conv_bf16<<<512, 256, 0, stream>>>(fcw, FCW, 524288L);
  prep_bias<<<1, 512, 0, stream>>>(bih, bhh, b1, b2);

  dim3 blk(512);
  dim3 g1(500, 4);   // 64000/128 x 512/128
  dim3 g2(500, 8);   // 64000/128 x 1024/128

  // layer 1
  gemm_bt<1><<<g1, blk, 0, stream>>>(Xb, Wih1, b1, Ub, 64000, 512, 512);
  rnn_rec<<<8, blk, 0, stream>>>(Whh1, Ub, Hb, Hdump, hid);
  // layer 2
  gemm_bt<1><<<g1, blk, 0, stream>>>(Hb, Wih2, b2, Ub, 64000, 512, 512);
  rnn_rec<<<8, blk, 0, stream>>>(Whh2, Ub, Hb, Hdump, hid + 64000);
  // FC head
  gemm_bt<0><<<g2, blk, 0, stream>>>(Hb, FCW, fcb, d_out, 64000, 1024, 512);

  (void)in_sizes; (void)n_in; (void)out_size; (void)ws_size;
}